// Round 3
// baseline (177.883 us; speedup 1.0000x reference)
//
#include <hip/hip_runtime.h>

typedef unsigned short u16;
typedef __attribute__((ext_vector_type(4))) float f32x4;
typedef __attribute__((ext_vector_type(8))) short short8;

#define AS1 __attribute__((address_space(1)))
#define AS3 __attribute__((address_space(3)))

#define B_  2
#define T_  2048
#define C_  1024
#define H_  16
#define HD_ 64
#define N3C 3072
#define BT_ 4096

__device__ __forceinline__ u16 f2bf(float x) {
    unsigned u = __float_as_uint(x);
    u += 0x7fff + ((u >> 16) & 1);          // RTNE
    return (u16)(u >> 16);
}

// one-instruction packed fp32x2 -> bf16x2 (RTNE), gfx950
__device__ __forceinline__ unsigned cvt_pk_bf16(float a, float b) {
    unsigned r;
    asm("v_cvt_pk_bf16_f32 %0, %1, %2" : "=v"(r) : "v"(a), "v"(b));
    return r;
}

// ---------------------------------------------------------------------------
// Fused conversion kernel: blocks [0,4096) = x fp32->bf16;
// [4096,4864) = Wqkv transpose; [4864,5120) = Wproj transpose.
// ---------------------------------------------------------------------------
__global__ __launch_bounds__(256)
void conv_all(const float* __restrict__ x, u16* __restrict__ xb,
              const float* __restrict__ Wq, u16* __restrict__ WqT,
              const float* __restrict__ Wp, u16* __restrict__ WpT) {
    __shared__ float tile[64][68];
    const int tid = threadIdx.x;
    const int b = blockIdx.x;
    if (b < 4096) {
        int i = b * 256 + tid;
        float4 f = ((const float4*)x)[i];
        uint2 o;
        o.x = cvt_pk_bf16(f.x, f.y);
        o.y = cvt_pk_bf16(f.z, f.w);
        ((uint2*)xb)[i] = o;
        return;
    }
    const float* W; u16* WT; int N, k0, n0;
    if (b < 4096 + 768) {
        int bb = b - 4096; W = Wq; WT = WqT; N = N3C;
        n0 = (bb % 48) * 64; k0 = (bb / 48) * 64;
    } else {
        int bb = b - 4864; W = Wp; WT = WpT; N = C_;
        n0 = (bb % 16) * 64; k0 = (bb / 16) * 64;
    }
    #pragma unroll
    for (int i = 0; i < 4; ++i) {
        int slot = tid + i * 256;
        int row = slot >> 4, c4 = (slot & 15) * 4;
        *(float4*)&tile[row][c4] = *(const float4*)&W[(size_t)(k0 + row) * N + n0 + c4];
    }
    __syncthreads();
    #pragma unroll
    for (int i = 0; i < 4; ++i) {
        int slot = tid + i * 256;
        int nn = slot >> 4, k4 = (slot & 15) * 4;
        uint2 o;
        o.x = cvt_pk_bf16(tile[k4 + 0][nn], tile[k4 + 1][nn]);
        o.y = cvt_pk_bf16(tile[k4 + 2][nn], tile[k4 + 3][nn]);
        *(uint2*)&WT[(size_t)(n0 + nn) * 1024 + k0 + k4] = o;
    }
}

// ---------------------------------------------------------------------------
// QKV GEMM, 256(M)x192(N) tile / 8 waves / BK=64, 4 phases x 12 MFMA per
// K-tile, dbuf-2 LDS with counted vmcnt (never 0 in steady state).
// Proven 0-conflict LDS swizzle: 128B rows, chunk=(lane&7)^srow on write
// (pre-swizzled global source), chunk=((s*4+quad)^(l15&7)) on read.
// ---------------------------------------------------------------------------
__global__ __launch_bounds__(512, 2)
void qkv_gemm(const u16* __restrict__ A, const u16* __restrict__ BT,
              const float* __restrict__ bias,
              u16* __restrict__ q, u16* __restrict__ k, u16* __restrict__ vT) {
    __shared__ __align__(16) u16 As[2][256 * 64];
    __shared__ __align__(16) u16 Bs[2][192 * 64];
    const int tid  = threadIdx.x;
    const int lane = tid & 63, w = tid >> 6;          // 8 waves
    const int wr = w >> 2, wc = w & 3;                // 2M x 4N wave grid
    const int l15 = lane & 15, quad = lane >> 4;
    const int srow = lane >> 3, schunk = (lane & 7) ^ srow;

    // bijective XCD swizzle: 256 blocks, 32/XCD; XCD x owns M-panels {2x,2x+1}
    const int bid = blockIdx.x;
    const int xcd = bid & 7, rr = bid >> 3;           // rr in [0,32)
    const int bm = (xcd << 1) | (rr & 1);             // [0,16)
    const int bn = rr >> 1;                           // [0,16)
    const int m0 = bm * 256, n0 = bn * 192;

    // per-wave global staging bases (pre-swizzled source, linear LDS dest)
    const u16* gA = A  + (size_t)(m0 + w * 8  + srow) * 1024 + schunk * 8;
    const u16* gB = BT + (size_t)(n0 + w * 24 + srow) * 1024 + schunk * 8;

    auto stA = [&](int t, int qq) {   // 8 rows at w*8 + qq*64
        __builtin_amdgcn_global_load_lds(
            (const AS1 void*)(gA + (size_t)qq * 64 * 1024 + t * 64),
            (AS3 void*)(&As[t & 1][(w * 8 + qq * 64) * 64]), 16, 0, 0);
    };
    auto stB = [&](int t, int g) {    // 8 rows at w*24 + g*8
        __builtin_amdgcn_global_load_lds(
            (const AS1 void*)(gB + (size_t)g * 8 * 1024 + t * 64),
            (AS3 void*)(&Bs[t & 1][(w * 24 + g * 8) * 64]), 16, 0, 0);
    };

    f32x4 acc[8][3] = {};

    // prologue: tile 0 in order B0,B1,B2,Aq0,Aq2,Aq1,Aq3 -> steady-state wait
    stB(0, 0); stB(0, 1); stB(0, 2); stA(0, 0); stA(0, 2); stA(0, 1); stA(0, 3);
    asm volatile("s_waitcnt vmcnt(2)\n\ts_barrier" ::: "memory");

    #pragma unroll 1
    for (int t = 0; t < 16; ++t) {
        const u16* Ac = &As[t & 1][0];
        const u16* Bc = &Bs[t & 1][0];
        const bool st = (t < 15);
        short8 a[4], b[3];

        // ---- ph0: s=0, mf 0-3 (needs B all + A even quarters) ----
        {
            const int xo = (quad ^ (l15 & 7)) * 8;
            #pragma unroll
            for (int mf = 0; mf < 4; ++mf)
                a[mf] = *(const short8*)&Ac[(wr * 128 + mf * 16 + l15) * 64 + xo];
            #pragma unroll
            for (int nf = 0; nf < 3; ++nf)
                b[nf] = *(const short8*)&Bc[(wc * 48 + nf * 16 + l15) * 64 + xo];
            if (st) { stB(t + 1, 0); stB(t + 1, 1); }
            asm volatile("s_barrier\n\ts_waitcnt lgkmcnt(0)" ::: "memory");
            __builtin_amdgcn_s_setprio(1);
            #pragma unroll
            for (int mf = 0; mf < 4; ++mf)
                #pragma unroll
                for (int nf = 0; nf < 3; ++nf)
                    acc[mf][nf] = __builtin_amdgcn_mfma_f32_16x16x32_bf16(a[mf], b[nf], acc[mf][nf], 0, 0, 0);
            __builtin_amdgcn_s_setprio(0);
            // drain this tile's A-odd quarters (oldest in flight) before ph1
            if (st) asm volatile("s_waitcnt vmcnt(2)\n\ts_barrier" ::: "memory");
            else    asm volatile("s_waitcnt vmcnt(0)\n\ts_barrier" ::: "memory");
        }
        // ---- ph1: s=0, mf 4-7 (b reused in regs) ----
        {
            const int xo = (quad ^ (l15 & 7)) * 8;
            #pragma unroll
            for (int mf = 0; mf < 4; ++mf)
                a[mf] = *(const short8*)&Ac[(wr * 128 + (4 + mf) * 16 + l15) * 64 + xo];
            if (st) { stB(t + 1, 2); stA(t + 1, 0); }
            asm volatile("s_barrier\n\ts_waitcnt lgkmcnt(0)" ::: "memory");
            __builtin_amdgcn_s_setprio(1);
            #pragma unroll
            for (int mf = 0; mf < 4; ++mf)
                #pragma unroll
                for (int nf = 0; nf < 3; ++nf)
                    acc[4 + mf][nf] = __builtin_amdgcn_mfma_f32_16x16x32_bf16(a[mf], b[nf], acc[4 + mf][nf], 0, 0, 0);
            __builtin_amdgcn_s_setprio(0);
            asm volatile("s_barrier" ::: "memory");
        }
        // ---- ph2: s=1, mf 0-3 (+ b s=1) ----
        {
            const int xo = ((4 + quad) ^ (l15 & 7)) * 8;
            #pragma unroll
            for (int mf = 0; mf < 4; ++mf)
                a[mf] = *(const short8*)&Ac[(wr * 128 + mf * 16 + l15) * 64 + xo];
            #pragma unroll
            for (int nf = 0; nf < 3; ++nf)
                b[nf] = *(const short8*)&Bc[(wc * 48 + nf * 16 + l15) * 64 + xo];
            if (st) stA(t + 1, 2);
            asm volatile("s_barrier\n\ts_waitcnt lgkmcnt(0)" ::: "memory");
            __builtin_amdgcn_s_setprio(1);
            #pragma unroll
            for (int mf = 0; mf < 4; ++mf)
                #pragma unroll
                for (int nf = 0; nf < 3; ++nf)
                    acc[mf][nf] = __builtin_amdgcn_mfma_f32_16x16x32_bf16(a[mf], b[nf], acc[mf][nf], 0, 0, 0);
            __builtin_amdgcn_s_setprio(0);
            asm volatile("s_barrier" ::: "memory");
        }
        // ---- ph3: s=1, mf 4-7 ----
        {
            const int xo = ((4 + quad) ^ (l15 & 7)) * 8;
            #pragma unroll
            for (int mf = 0; mf < 4; ++mf)
                a[mf] = *(const short8*)&Ac[(wr * 128 + (4 + mf) * 16 + l15) * 64 + xo];
            if (st) { stA(t + 1, 1); stA(t + 1, 3); }
            asm volatile("s_barrier\n\ts_waitcnt lgkmcnt(0)" ::: "memory");
            __builtin_amdgcn_s_setprio(1);
            #pragma unroll
            for (int mf = 0; mf < 4; ++mf)
                #pragma unroll
                for (int nf = 0; nf < 3; ++nf)
                    acc[4 + mf][nf] = __builtin_amdgcn_mfma_f32_16x16x32_bf16(a[mf], b[nf], acc[4 + mf][nf], 0, 0, 0);
            __builtin_amdgcn_s_setprio(0);
            // drain next tile's B + A-even (oldest 5 of 7 in flight)
            if (st) asm volatile("s_waitcnt vmcnt(2)\n\ts_barrier" ::: "memory");
            else    asm volatile("s_barrier" ::: "memory");
        }
    }

    // ---- epilogue: bias + scatter (q scaled for exp2 attention) ----
    const float QSCALE = 0.125f * 1.4426950408889634f;   // 1/8 * log2(e)
    #pragma unroll
    for (int nf = 0; nf < 3; ++nf) {
        const int n = n0 + wc * 48 + nf * 16 + l15;
        const int which = n >> 10;                        // wave-uniform
        const int nl = n & 1023, h = nl >> 6, d = nl & 63;
        const float bv = bias[n];
        #pragma unroll
        for (int mf = 0; mf < 8; ++mf) {
            const int mb = m0 + wr * 128 + mf * 16 + quad * 4;
            const int bb = mb >> 11, t0 = mb & 2047;
            f32x4 v4 = acc[mf][nf];
            if (which == 0) {
                size_t base = ((size_t)(bb * H_ + h) * T_ + t0) * HD_ + d;
                #pragma unroll
                for (int r = 0; r < 4; ++r)
                    q[base + (size_t)r * HD_] = f2bf((v4[r] + bv) * QSCALE);
            } else if (which == 1) {
                size_t base = ((size_t)(bb * H_ + h) * T_ + t0) * HD_ + d;
                #pragma unroll
                for (int r = 0; r < 4; ++r)
                    k[base + (size_t)r * HD_] = f2bf(v4[r] + bv);
            } else {
                uint2 o;
                o.x = cvt_pk_bf16(v4[0] + bv, v4[1] + bv);
                o.y = cvt_pk_bf16(v4[2] + bv, v4[3] + bv);
                *(uint2*)&vT[((size_t)(bb * H_ + h) * HD_ + d) * T_ + t0] = o;
            }
        }
    }
}

// ---------------------------------------------------------------------------
// Flash attention v8: 2x2 wave decomposition (kh=key-half, qh=q-half).
// Each wave owns 32 keys x 32 q-cols: K frags 4 b128 + V frags 4 b128 per
// phase (HALF of v7's 16 -- waves no longer redundantly read the full tile).
// Same MFMA count (QK 8 + PV 8 per wave).  P lives in a dedicated 8 KB LDS
// buffer with per-wave-disjoint (row,chunk) ownership -> P sync stays
// wave-local; mid lgkm+barrier retained as the stage-safety barrier.
// Cross-kh O/l reduce through dead Vs/Ps once per block.
// ---------------------------------------------------------------------------
__global__ __launch_bounds__(256, 4)
void attn(const u16* __restrict__ q, const u16* __restrict__ k,
          const u16* __restrict__ vT, u16* __restrict__ y) {
    __shared__ __align__(16) u16 Ks[2 * 64 * 64];
    __shared__ __align__(16) u16 Vs[2 * 64 * 64];
    __shared__ __align__(16) u16 Ps[64 * 64];
    const int tid = threadIdx.x;
    const int lane = tid & 63, w = tid >> 6;
    const int kh = w >> 1, qh = w & 1;              // 2x2 wave grid
    const int l15 = lane & 15, quad = lane >> 4;
    const int srow = lane >> 3, schunk = (lane & 7) ^ srow;
    const int idx = blockIdx.x;
    const int bh = idx & 31;                        // bh%8 = XCD locality
    const int qt = 31 - (idx >> 5);                 // heavy first
    const u16* qp = q  + (size_t)bh * T_ * HD_;
    const u16* kp = k  + (size_t)bh * T_ * HD_;
    const u16* vp = vT + (size_t)bh * HD_ * T_;

    // q frags: this wave's 32 q-rows (qh*32..), 2 qg x 2 s halves of HD
    short8 qf[2][2];
    #pragma unroll
    for (int qg = 0; qg < 2; ++qg) {
        const int qrow = qt * 64 + qh * 32 + qg * 16 + l15;
        #pragma unroll
        for (int s = 0; s < 2; ++s)
            qf[qg][s] = *(const short8*)&qp[(size_t)qrow * HD_ + s * 32 + quad * 8];
    }

    auto stage = [&](int buf, int kt) {
        const int kb = kt * 64;
        // wave-local fence: prior pb/frag reads retire before DMA issue
        asm volatile("s_waitcnt lgkmcnt(0)" ::: "memory");
        #pragma unroll
        for (int j = 0; j < 2; ++j) {
            int row = w * 16 + j * 8 + srow;
            __builtin_amdgcn_global_load_lds(
                (const AS1 void*)(kp + (size_t)(kb + row) * HD_ + schunk * 8),
                (AS3 void*)(Ks + buf * (64 * 64) + (w * 16 + j * 8) * 64), 16, 0, 0);
            __builtin_amdgcn_global_load_lds(
                (const AS1 void*)(vp + (size_t)row * T_ + kb + schunk * 8),
                (AS3 void*)(Vs + buf * (64 * 64) + (w * 16 + j * 8) * 64), 16, 0, 0);
        }
    };

    f32x4 o[4][2] = {};
    float l[2] = {0.f, 0.f};
    stage(0, 0);

    for (int kt = 0; kt <= qt; ++kt) {
        const int cur = kt & 1;
        if (kt < qt) {
            stage(cur ^ 1, kt + 1);
            asm volatile("s_waitcnt vmcnt(4)\n\ts_barrier" ::: "memory");
        } else {
            asm volatile("s_waitcnt vmcnt(0)\n\ts_barrier" ::: "memory");
        }
        const u16* Kc = Ks + cur * (64 * 64);
        const u16* Vc = Vs + cur * (64 * 64);

        // K: own 32 keys (2 x 16-row groups) x full HD; V: full d x own 32 keys
        short8 ka[2][2], va[4];
        #pragma unroll
        for (int t = 0; t < 2; ++t)
            #pragma unroll
            for (int s = 0; s < 2; ++s)
                ka[t][s] = *(const short8*)&Kc[(kh * 32 + t * 16 + l15) * 64 + (((s * 4 + quad) ^ (l15 & 7)) * 8)];
        #pragma unroll
        for (int n = 0; n < 4; ++n)
            va[n] = *(const short8*)&Vc[(n * 16 + l15) * 64 + (((kh * 4 + quad) ^ (l15 & 7)) * 8)];
        // all waves' K/V frag reads complete before next stage overwrites
        asm volatile("s_waitcnt lgkmcnt(0)\n\ts_barrier" ::: "memory");

        // S^T = K.Q^T  (rows = own keys, cols = own q);  scores already *log2e
        f32x4 st[2][2] = {};
        #pragma unroll
        for (int s = 0; s < 2; ++s)
            #pragma unroll
            for (int t = 0; t < 2; ++t)
                #pragma unroll
                for (int qg = 0; qg < 2; ++qg)
                    st[t][qg] = __builtin_amdgcn_mfma_f32_16x16x32_bf16(ka[t][s], qf[qg][s], st[t][qg], 0, 0, 0);

        float pe[2][2][4];
        #pragma unroll
        for (int t = 0; t < 2; ++t)
            #pragma unroll
            for (int qg = 0; qg < 2; ++qg)
                #pragma unroll
                for (int r = 0; r < 4; ++r)
                    pe[t][qg][r] = exp2f(st[t][qg][r]);
        if (kt == qt) {                              // causal mask (local idx)
            #pragma unroll
            for (int t = 0; t < 2; ++t)
                #pragma unroll
                for (int qg = 0; qg < 2; ++qg)
                    #pragma unroll
                    for (int r = 0; r < 4; ++r)
                        if ((kh * 32 + t * 16 + quad * 4 + r) > (qh * 32 + qg * 16 + l15))
                            pe[t][qg][r] = 0.f;
        }
        #pragma unroll
        for (int qg = 0; qg < 2; ++qg) {
            float ps = 0.f;
            #pragma unroll
            for (int t = 0; t < 2; ++t)
                #pragma unroll
                for (int r = 0; r < 4; ++r)
                    ps += pe[t][qg][r];
            l[qg] += ps;
        }

        // P -> Ps rows = q (qh*32 block), key chunks kh*4.. (wave-disjoint)
        #pragma unroll
        for (int t = 0; t < 2; ++t)
            #pragma unroll
            for (int qg = 0; qg < 2; ++qg) {
                int off = (((kh * 4 + t * 2 + (quad >> 1)) ^ (l15 & 7)) << 3) + (quad & 1) * 4;
                uint2 pk;
                pk.x = cvt_pk_bf16(pe[t][qg][0], pe[t][qg][1]);
                pk.y = cvt_pk_bf16(pe[t][qg][2], pe[t][qg][3]);
                *(uint2*)&Ps[(qh * 32 + qg * 16 + l15) * 64 + off] = pk;
            }
        asm volatile("s_waitcnt lgkmcnt(0)" ::: "memory");   // wave-local RT

        // O^T += V^T . P^T  over own 32 keys
        #pragma unroll
        for (int qg = 0; qg < 2; ++qg) {
            short8 pb = *(const short8*)&Ps[(qh * 32 + qg * 16 + l15) * 64 + (((kh * 4 + quad) ^ (l15 & 7)) << 3)];
            #pragma unroll
            for (int n = 0; n < 4; ++n)
                o[n][qg] = __builtin_amdgcn_mfma_f32_16x16x32_bf16(va[n], pb, o[n][qg], 0, 0, 0);
        }
    }

    // quad-reduce l (each lane -> total over its kh keys for q=qg*16+l15)
    l[0] += __shfl_xor(l[0], 16); l[0] += __shfl_xor(l[0], 32);
    l[1] += __shfl_xor(l[1], 16); l[1] += __shfl_xor(l[1], 32);

    // cross-kh combine through dead Vs (o) and Ps (l)
    float* ob = (float*)Vs;
    float* lb = (float*)Ps;
    asm volatile("s_waitcnt lgkmcnt(0)\n\ts_barrier" ::: "memory");
    if (kh == 1) {
        const int base = (qh * 64 + lane) * 32;
        #pragma unroll
        for (int n = 0; n < 4; ++n)
            #pragma unroll
            for (int qg = 0; qg < 2; ++qg)
                *(f32x4*)&ob[base + (n * 2 + qg) * 4] = o[n][qg];
        lb[(qh * 64 + lane) * 2 + 0] = l[0];
        lb[(qh * 64 + lane) * 2 + 1] = l[1];
    }
    asm volatile("s_waitcnt lgkmcnt(0)\n\ts_barrier" ::: "memory");
    if (kh == 0) {
        const int base = (qh * 64 + lane) * 32;
        float linv[2];
        linv[0] = 1.f / (l[0] + lb[(qh * 64 + lane) * 2 + 0]);
        linv[1] = 1.f / (l[1] + lb[(qh * 64 + lane) * 2 + 1]);
        const int bb = bh >> 4, h = bh & 15;
        #pragma unroll
        for (int qg = 0; qg < 2; ++qg) {
            const int qrow = qt * 64 + qh * 32 + qg * 16 + l15;
            #pragma unroll
            for (int n = 0; n < 4; ++n) {
                f32x4 ov = o[n][qg] + *(const f32x4*)&ob[base + (n * 2 + qg) * 4];
                uint2 pk;
                pk.x = cvt_pk_bf16(ov[0] * linv[qg], ov[1] * linv[qg]);
                pk.y = cvt_pk_bf16(ov[2] * linv[qg], ov[3] * linv[qg]);
                *(uint2*)&y[((size_t)(bb * T_ + qrow)) * C_ + h * 64 + n * 16 + quad * 4] = pk;
            }
        }
    }
}

// ---------------------------------------------------------------------------
// Output projection: y[4096][1024] @ WprojT[1024][1024]^T + bias -> fp32 out.
// 128x64 tile (512 blocks, 48 KB LDS -> 3 blocks/CU).
// ---------------------------------------------------------------------------
__global__ __launch_bounds__(256, 3)
void proj_gemm(const u16* __restrict__ A, const u16* __restrict__ BT,
               const float* __restrict__ bias, float* __restrict__ out) {
    __shared__ __align__(16) u16 As[2 * 128 * 64];
    __shared__ __align__(16) u16 Bs[2 * 64 * 64];
    const int m0 = blockIdx.y * 128, n0 = blockIdx.x * 64;
    const int tid = threadIdx.x;
    const int lane = tid & 63, w = tid >> 6;
    const int l15 = lane & 15, quad = lane >> 4;
    const int row0 = (w & 1) * 64, col0 = (w >> 1) * 32;
    const int srow = lane >> 3;
    const int schunk = (lane & 7) ^ srow;
    f32x4 acc[4][2] = {};

    auto stage = [&](int buf, int k0) {
        #pragma unroll
        for (int j = 0; j < 4; ++j) {
            int rbase = w * 32 + j * 8;
            const u16* ga = A + (size_t)(m0 + rbase + srow) * 1024 + k0 + schunk * 8;
            __builtin_amdgcn_global_load_lds((const AS1 void*)ga,
                (AS3 void*)(As + buf * (128 * 64) + rbase * 64), 16, 0, 0);
        }
        #pragma unroll
        for (int j = 0; j < 2; ++j) {
            int rbase = w * 16 + j * 8;
            const u16* gb = BT + (size_t)(n0 + rbase + srow) * 1024 + k0 + schunk * 8;
            __builtin_amdgcn_global_load_lds((const AS1 void*)gb,
                (AS3 void*)(Bs + buf * (64 * 64) + rbase * 64), 16, 0, 0);
        }
    };

    stage(0, 0);
    #pragma unroll
    for (int it = 0; it < 16; ++it) {
        const int cur = it & 1;
        if (it + 1 < 16) {
            stage(cur ^ 1, (it + 1) * 64);
            asm volatile("s_waitcnt vmcnt(6)\n\ts_barrier" ::: "memory");
        } else {
            asm volatile("s_waitcnt vmcnt(0)\n\ts_barrier" ::: "memory");
        }
        const u16* Ac = As + cur * (128 * 64);
        const u16* Bc = Bs + cur * (64 * 64);
        #pragma unroll
        for (int s = 0; s < 2; ++s) {
            short8 a[4], b[2];
            #pragma unroll
            for (int rt = 0; rt < 4; ++rt) {
                int row = row0 + rt * 16 + l15;
                a[rt] = *(const short8*)&Ac[row * 64 + (((s * 4 + quad) ^ (l15 & 7)) * 8)];
            }
            #pragma unroll
            for (int ct = 0; ct < 2; ++ct) {
                int row = col0 + ct * 16 + l15;
                b[ct] = *(const short8*)&Bs[cur * (64 * 64) + row * 64 + (((s * 4 + quad) ^ (l15 & 7)) * 8)];
            }
            #pragma unroll
            for (int rt = 0; rt < 4; ++rt)
                #pragma unroll
                for (int ct = 0; ct < 2; ++ct)
                    acc[rt][ct] = __builtin_amdgcn_mfma_f32_16x16x32_bf16(a[rt], b[ct], acc[rt][ct], 0, 0, 0);
        }
        asm volatile("s_waitcnt lgkmcnt(0)\n\ts_barrier" ::: "memory");
    }

    #pragma unroll
    for (int ct = 0; ct < 2; ++ct) {
        int n = n0 + col0 + ct * 16 + l15;
        float bv = bias[n];
        #pragma unroll
        for (int rt = 0; rt < 4; ++rt) {
            int mb = m0 + row0 + rt * 16 + quad * 4;
            f32x4 v4 = acc[rt][ct];
            #pragma unroll
            for (int r = 0; r < 4; ++r)
                out[(size_t)(mb + r) * 1024 + n] = v4[r] + bv;
        }
    }
}

// ---------------------------------------------------------------------------
extern "C" void kernel_launch(void* const* d_in, const int* in_sizes, int n_in,
                              void* d_out, int out_size, void* d_ws, size_t ws_size,
                              hipStream_t stream) {
    const float* x     = (const float*)d_in[0];
    const float* Wqkv  = (const float*)d_in[1];
    const float* bqkv  = (const float*)d_in[2];
    const float* Wproj = (const float*)d_in[3];
    const float* bproj = (const float*)d_in[4];

    u16* xb     = (u16*)d_ws;
    u16* WqkvT  = xb + (size_t)4 * 1024 * 1024;
    u16* WprojT = WqkvT + (size_t)3 * 1024 * 1024;
    u16* q      = WprojT + (size_t)1024 * 1024;
    u16* kk     = q + (size_t)4 * 1024 * 1024;
    u16* vT     = kk + (size_t)4 * 1024 * 1024;
    u16* y      = vT + (size_t)4 * 1024 * 1024;

    conv_all<<<5120, 256, 0, stream>>>(x, xb, Wqkv, WqkvT, Wproj, WprojT);
    qkv_gemm<<<256, 512, 0, stream>>>(xb, WqkvT, bqkv, q, kk, vT);
    attn<<<1024, 256, 0, stream>>>(q, kk, vT, y);
    proj_gemm<<<dim3(C_ / 64, BT_ / 128), 256, 0, stream>>>(y, WprojT, bproj, (float*)d_out);
}

// Round 4
// 173.836 us; speedup vs baseline: 1.0233x; 1.0233x over previous
//
#include <hip/hip_runtime.h>

typedef unsigned short u16;
typedef __attribute__((ext_vector_type(4))) float f32x4;
typedef __attribute__((ext_vector_type(8))) short short8;
typedef __attribute__((ext_vector_type(4))) int i32x4;

#define AS1 __attribute__((address_space(1)))
#define AS3 __attribute__((address_space(3)))

#define B_  2
#define T_  2048
#define C_  1024
#define H_  16
#define HD_ 64
#define N3C 3072
#define BT_ 4096

__device__ __forceinline__ u16 f2bf(float x) {
    unsigned u = __float_as_uint(x);
    u += 0x7fff + ((u >> 16) & 1);          // RTNE
    return (u16)(u >> 16);
}

// one-instruction packed fp32x2 -> bf16x2 (RTNE), gfx950
__device__ __forceinline__ unsigned cvt_pk_bf16(float a, float b) {
    unsigned r;
    asm("v_cvt_pk_bf16_f32 %0, %1, %2" : "=v"(r) : "v"(a), "v"(b));
    return r;
}

// ---------------------------------------------------------------------------
// Fused conversion kernel: blocks [0,4096) = x fp32->bf16;
// [4096,4864) = Wqkv transpose; [4864,5120) = Wproj transpose.
// ---------------------------------------------------------------------------
__global__ __launch_bounds__(256)
void conv_all(const float* __restrict__ x, u16* __restrict__ xb,
              const float* __restrict__ Wq, u16* __restrict__ WqT,
              const float* __restrict__ Wp, u16* __restrict__ WpT) {
    __shared__ float tile[64][68];
    const int tid = threadIdx.x;
    const int b = blockIdx.x;
    if (b < 4096) {
        int i = b * 256 + tid;
        float4 f = ((const float4*)x)[i];
        uint2 o;
        o.x = cvt_pk_bf16(f.x, f.y);
        o.y = cvt_pk_bf16(f.z, f.w);
        ((uint2*)xb)[i] = o;
        return;
    }
    const float* W; u16* WT; int N, k0, n0;
    if (b < 4096 + 768) {
        int bb = b - 4096; W = Wq; WT = WqT; N = N3C;
        n0 = (bb % 48) * 64; k0 = (bb / 48) * 64;
    } else {
        int bb = b - 4864; W = Wp; WT = WpT; N = C_;
        n0 = (bb % 16) * 64; k0 = (bb / 16) * 64;
    }
    #pragma unroll
    for (int i = 0; i < 4; ++i) {
        int slot = tid + i * 256;
        int row = slot >> 4, c4 = (slot & 15) * 4;
        *(float4*)&tile[row][c4] = *(const float4*)&W[(size_t)(k0 + row) * N + n0 + c4];
    }
    __syncthreads();
    #pragma unroll
    for (int i = 0; i < 4; ++i) {
        int slot = tid + i * 256;
        int nn = slot >> 4, k4 = (slot & 15) * 4;
        uint2 o;
        o.x = cvt_pk_bf16(tile[k4 + 0][nn], tile[k4 + 1][nn]);
        o.y = cvt_pk_bf16(tile[k4 + 2][nn], tile[k4 + 3][nn]);
        *(uint2*)&WT[(size_t)(n0 + nn) * 1024 + k0 + k4] = o;
    }
}

// ---------------------------------------------------------------------------
// QKV GEMM, 256(M)x192(N) tile / 8 waves / BK=64, 4 phases x 12 MFMA per
// K-tile, dbuf-2 LDS with counted vmcnt (never 0 in steady state).
// Proven 0-conflict LDS swizzle: 128B rows, chunk=(lane&7)^srow on write
// (pre-swizzled global source), chunk=((s*4+quad)^(l15&7)) on read.
// ---------------------------------------------------------------------------
__global__ __launch_bounds__(512, 2)
void qkv_gemm(const u16* __restrict__ A, const u16* __restrict__ BT,
              const float* __restrict__ bias,
              u16* __restrict__ q, u16* __restrict__ k, u16* __restrict__ vT) {
    __shared__ __align__(16) u16 As[2][256 * 64];
    __shared__ __align__(16) u16 Bs[2][192 * 64];
    const int tid  = threadIdx.x;
    const int lane = tid & 63, w = tid >> 6;          // 8 waves
    const int wr = w >> 2, wc = w & 3;                // 2M x 4N wave grid
    const int l15 = lane & 15, quad = lane >> 4;
    const int srow = lane >> 3, schunk = (lane & 7) ^ srow;

    // bijective XCD swizzle: 256 blocks, 32/XCD; XCD x owns M-panels {2x,2x+1}
    const int bid = blockIdx.x;
    const int xcd = bid & 7, rr = bid >> 3;           // rr in [0,32)
    const int bm = (xcd << 1) | (rr & 1);             // [0,16)
    const int bn = rr >> 1;                           // [0,16)
    const int m0 = bm * 256, n0 = bn * 192;

    // per-wave global staging bases (pre-swizzled source, linear LDS dest)
    const u16* gA = A  + (size_t)(m0 + w * 8  + srow) * 1024 + schunk * 8;
    const u16* gB = BT + (size_t)(n0 + w * 24 + srow) * 1024 + schunk * 8;

    auto stA = [&](int t, int qq) {   // 8 rows at w*8 + qq*64
        __builtin_amdgcn_global_load_lds(
            (const AS1 void*)(gA + (size_t)qq * 64 * 1024 + t * 64),
            (AS3 void*)(&As[t & 1][(w * 8 + qq * 64) * 64]), 16, 0, 0);
    };
    auto stB = [&](int t, int g) {    // 8 rows at w*24 + g*8
        __builtin_amdgcn_global_load_lds(
            (const AS1 void*)(gB + (size_t)g * 8 * 1024 + t * 64),
            (AS3 void*)(&Bs[t & 1][(w * 24 + g * 8) * 64]), 16, 0, 0);
    };

    f32x4 acc[8][3] = {};

    // prologue: tile 0 in order B0,B1,B2,Aq0,Aq2,Aq1,Aq3 -> steady-state wait
    stB(0, 0); stB(0, 1); stB(0, 2); stA(0, 0); stA(0, 2); stA(0, 1); stA(0, 3);
    asm volatile("s_waitcnt vmcnt(2)\n\ts_barrier" ::: "memory");

    #pragma unroll 1
    for (int t = 0; t < 16; ++t) {
        const u16* Ac = &As[t & 1][0];
        const u16* Bc = &Bs[t & 1][0];
        const bool st = (t < 15);
        short8 a[4], b[3];

        // ---- ph0: s=0, mf 0-3 (needs B all + A even quarters) ----
        {
            const int xo = (quad ^ (l15 & 7)) * 8;
            #pragma unroll
            for (int mf = 0; mf < 4; ++mf)
                a[mf] = *(const short8*)&Ac[(wr * 128 + mf * 16 + l15) * 64 + xo];
            #pragma unroll
            for (int nf = 0; nf < 3; ++nf)
                b[nf] = *(const short8*)&Bc[(wc * 48 + nf * 16 + l15) * 64 + xo];
            if (st) { stB(t + 1, 0); stB(t + 1, 1); }
            asm volatile("s_barrier\n\ts_waitcnt lgkmcnt(0)" ::: "memory");
            __builtin_amdgcn_s_setprio(1);
            #pragma unroll
            for (int mf = 0; mf < 4; ++mf)
                #pragma unroll
                for (int nf = 0; nf < 3; ++nf)
                    acc[mf][nf] = __builtin_amdgcn_mfma_f32_16x16x32_bf16(a[mf], b[nf], acc[mf][nf], 0, 0, 0);
            __builtin_amdgcn_s_setprio(0);
            // drain this tile's A-odd quarters (oldest in flight) before ph1
            if (st) asm volatile("s_waitcnt vmcnt(2)\n\ts_barrier" ::: "memory");
            else    asm volatile("s_waitcnt vmcnt(0)\n\ts_barrier" ::: "memory");
        }
        // ---- ph1: s=0, mf 4-7 (b reused in regs) ----
        {
            const int xo = (quad ^ (l15 & 7)) * 8;
            #pragma unroll
            for (int mf = 0; mf < 4; ++mf)
                a[mf] = *(const short8*)&Ac[(wr * 128 + (4 + mf) * 16 + l15) * 64 + xo];
            if (st) { stB(t + 1, 2); stA(t + 1, 0); }
            asm volatile("s_barrier\n\ts_waitcnt lgkmcnt(0)" ::: "memory");
            __builtin_amdgcn_s_setprio(1);
            #pragma unroll
            for (int mf = 0; mf < 4; ++mf)
                #pragma unroll
                for (int nf = 0; nf < 3; ++nf)
                    acc[4 + mf][nf] = __builtin_amdgcn_mfma_f32_16x16x32_bf16(a[mf], b[nf], acc[4 + mf][nf], 0, 0, 0);
            __builtin_amdgcn_s_setprio(0);
            asm volatile("s_barrier" ::: "memory");
        }
        // ---- ph2: s=1, mf 0-3 (+ b s=1) ----
        {
            const int xo = ((4 + quad) ^ (l15 & 7)) * 8;
            #pragma unroll
            for (int mf = 0; mf < 4; ++mf)
                a[mf] = *(const short8*)&Ac[(wr * 128 + mf * 16 + l15) * 64 + xo];
            #pragma unroll
            for (int nf = 0; nf < 3; ++nf)
                b[nf] = *(const short8*)&Bc[(wc * 48 + nf * 16 + l15) * 64 + xo];
            if (st) stA(t + 1, 2);
            asm volatile("s_barrier\n\ts_waitcnt lgkmcnt(0)" ::: "memory");
            __builtin_amdgcn_s_setprio(1);
            #pragma unroll
            for (int mf = 0; mf < 4; ++mf)
                #pragma unroll
                for (int nf = 0; nf < 3; ++nf)
                    acc[mf][nf] = __builtin_amdgcn_mfma_f32_16x16x32_bf16(a[mf], b[nf], acc[mf][nf], 0, 0, 0);
            __builtin_amdgcn_s_setprio(0);
            asm volatile("s_barrier" ::: "memory");
        }
        // ---- ph3: s=1, mf 4-7 ----
        {
            const int xo = ((4 + quad) ^ (l15 & 7)) * 8;
            #pragma unroll
            for (int mf = 0; mf < 4; ++mf)
                a[mf] = *(const short8*)&Ac[(wr * 128 + (4 + mf) * 16 + l15) * 64 + xo];
            if (st) { stA(t + 1, 1); stA(t + 1, 3); }
            asm volatile("s_barrier\n\ts_waitcnt lgkmcnt(0)" ::: "memory");
            __builtin_amdgcn_s_setprio(1);
            #pragma unroll
            for (int mf = 0; mf < 4; ++mf)
                #pragma unroll
                for (int nf = 0; nf < 3; ++nf)
                    acc[4 + mf][nf] = __builtin_amdgcn_mfma_f32_16x16x32_bf16(a[mf], b[nf], acc[4 + mf][nf], 0, 0, 0);
            __builtin_amdgcn_s_setprio(0);
            // drain next tile's B + A-even (oldest 5 of 7 in flight)
            if (st) asm volatile("s_waitcnt vmcnt(2)\n\ts_barrier" ::: "memory");
            else    asm volatile("s_barrier" ::: "memory");
        }
    }

    // ---- epilogue: bias + scatter (q scaled for exp2 attention) ----
    const float QSCALE = 0.125f * 1.4426950408889634f;   // 1/8 * log2(e)
    #pragma unroll
    for (int nf = 0; nf < 3; ++nf) {
        const int n = n0 + wc * 48 + nf * 16 + l15;
        const int which = n >> 10;                        // wave-uniform
        const int nl = n & 1023, h = nl >> 6, d = nl & 63;
        const float bv = bias[n];
        #pragma unroll
        for (int mf = 0; mf < 8; ++mf) {
            const int mb = m0 + wr * 128 + mf * 16 + quad * 4;
            const int bb = mb >> 11, t0 = mb & 2047;
            f32x4 v4 = acc[mf][nf];
            if (which == 0) {
                size_t base = ((size_t)(bb * H_ + h) * T_ + t0) * HD_ + d;
                #pragma unroll
                for (int r = 0; r < 4; ++r)
                    q[base + (size_t)r * HD_] = f2bf((v4[r] + bv) * QSCALE);
            } else if (which == 1) {
                size_t base = ((size_t)(bb * H_ + h) * T_ + t0) * HD_ + d;
                #pragma unroll
                for (int r = 0; r < 4; ++r)
                    k[base + (size_t)r * HD_] = f2bf(v4[r] + bv);
            } else {
                uint2 o;
                o.x = cvt_pk_bf16(v4[0] + bv, v4[1] + bv);
                o.y = cvt_pk_bf16(v4[2] + bv, v4[3] + bv);
                *(uint2*)&vT[((size_t)(bb * H_ + h) * HD_ + d) * T_ + t0] = o;
            }
        }
    }
}

// ---------------------------------------------------------------------------
// Flash attention v9 = v7 structure (4 waves, wave owns 16 q-rows, full 64-key
// tiles) with the P LDS round-trip replaced by in-register redistribution:
// P^T held as st[ct] (key=ct*16+quad*4+r, q=l15) is packed to bf16 pairs and
// moved to PV's B-operand layout (key octet = quad*8+j) via 16 ds_bpermute +
// 8 cndmask (dual gather, select by own quad>>1).  No P buffer, no store->load
// LDS dependency, and the mid lgkm+barrier disappears: ONE barrier per phase
// (top vmcnt(0)+barrier).  Safety: all waves' phase-(t-1) frag reads retire
// before their MFMAs (compiler lgkm deps), hence before the phase-t barrier;
// the tile-(t+1) DMA (into buf cur^1) is issued after that barrier.
// ---------------------------------------------------------------------------
__global__ __launch_bounds__(256, 4)
void attn(const u16* __restrict__ q, const u16* __restrict__ k,
          const u16* __restrict__ vT, u16* __restrict__ y) {
    __shared__ __align__(16) u16 Ks[2 * 64 * 64];
    __shared__ __align__(16) u16 Vs[2 * 64 * 64];
    const int tid = threadIdx.x;
    const int lane = tid & 63, w = tid >> 6;
    const int l15 = lane & 15, quad = lane >> 4;
    const int srow = lane >> 3, schunk = (lane & 7) ^ srow;
    const int idx = blockIdx.x;
    const int bh = idx & 31;                        // bh%8 = XCD locality
    const int qt = 31 - (idx >> 5);                 // heavy first
    const u16* qp = q  + (size_t)bh * T_ * HD_;
    const u16* kp = k  + (size_t)bh * T_ * HD_;
    const u16* vp = vT + (size_t)bh * HD_ * T_;

    const int qrow = qt * 64 + w * 16 + l15;
    short8 qf[2];
    #pragma unroll
    for (int s = 0; s < 2; ++s)
        qf[s] = *(const short8*)&qp[(size_t)qrow * HD_ + s * 32 + quad * 8];

    auto stage = [&](int buf, int kt) {
        const int kb = kt * 64;
        #pragma unroll
        for (int j = 0; j < 2; ++j) {
            int row = w * 16 + j * 8 + srow;
            __builtin_amdgcn_global_load_lds(
                (const AS1 void*)(kp + (size_t)(kb + row) * HD_ + schunk * 8),
                (AS3 void*)(Ks + buf * (64 * 64) + (w * 16 + j * 8) * 64), 16, 0, 0);
            __builtin_amdgcn_global_load_lds(
                (const AS1 void*)(vp + (size_t)row * T_ + kb + schunk * 8),
                (AS3 void*)(Vs + buf * (64 * 64) + (w * 16 + j * 8) * 64), 16, 0, 0);
        }
    };

    f32x4 o[4] = {};
    float l = 0.f;
    stage(0, 0);

    // bpermute gather addresses (bytes): pull from lane l15 + 32*(quad&1) (+16)
    const int a0 = (l15 + ((quad & 1) << 5)) << 2;
    const int a1 = a0 + 64;
    const bool hiq = (quad >> 1) != 0;

    for (int kt = 0; kt <= qt; ++kt) {
        const int kb = kt * 64;
        const int cur = kt & 1;
        // my DMAs for tile kt landed; all waves synced (their DMAs landed too)
        asm volatile("s_waitcnt vmcnt(0)\n\ts_barrier" ::: "memory");
        const u16* Kc = Ks + cur * (64 * 64);
        const u16* Vc = Vs + cur * (64 * 64);

        short8 ka[4][2], va[4][2];
        #pragma unroll
        for (int ct = 0; ct < 4; ++ct)
            #pragma unroll
            for (int s = 0; s < 2; ++s) {
                int xo = ((s * 4 + quad) ^ (l15 & 7)) * 8;
                ka[ct][s] = *(const short8*)&Kc[(ct * 16 + l15) * 64 + xo];
                va[ct][s] = *(const short8*)&Vc[(ct * 16 + l15) * 64 + xo];
            }
        // prefetch next tile into the other buffer (disjoint from cur)
        if (kt < qt) stage(cur ^ 1, kt + 1);

        // S^T = K.Q^T  (C row = key, col = q = l15);  scores already *log2e
        f32x4 st[4] = {};
        #pragma unroll
        for (int s = 0; s < 2; ++s)
            #pragma unroll
            for (int ct = 0; ct < 4; ++ct)
                st[ct] = __builtin_amdgcn_mfma_f32_16x16x32_bf16(ka[ct][s], qf[s], st[ct], 0, 0, 0);

        float pe[16];
        #pragma unroll
        for (int ct = 0; ct < 4; ++ct)
            #pragma unroll
            for (int r = 0; r < 4; ++r)
                pe[ct * 4 + r] = exp2f(st[ct][r]);
        if (kt == qt) {                              // causal mask
            #pragma unroll
            for (int ct = 0; ct < 4; ++ct)
                #pragma unroll
                for (int r = 0; r < 4; ++r)
                    if ((kb + ct * 16 + quad * 4 + r) > qrow) pe[ct * 4 + r] = 0.f;
        }
        float psum = 0.f;
        #pragma unroll
        for (int i = 0; i < 16; ++i) psum += pe[i];
        l += psum;

        // pack P to bf16 pairs: pk[ct][i] = keys (ct*16+quad*4) + {2i, 2i+1}
        int pk[4][2];
        #pragma unroll
        for (int ct = 0; ct < 4; ++ct) {
            pk[ct][0] = (int)cvt_pk_bf16(pe[ct * 4 + 0], pe[ct * 4 + 1]);
            pk[ct][1] = (int)cvt_pk_bf16(pe[ct * 4 + 2], pe[ct * 4 + 3]);
        }

        // redistribute to B-operand layout and do PV
        #pragma unroll
        for (int s = 0; s < 2; ++s) {
            int e0 = __builtin_amdgcn_ds_bpermute(a0, pk[2 * s + 0][0]);
            int g0 = __builtin_amdgcn_ds_bpermute(a0, pk[2 * s + 1][0]);
            int e1 = __builtin_amdgcn_ds_bpermute(a0, pk[2 * s + 0][1]);
            int g1 = __builtin_amdgcn_ds_bpermute(a0, pk[2 * s + 1][1]);
            int e2 = __builtin_amdgcn_ds_bpermute(a1, pk[2 * s + 0][0]);
            int g2 = __builtin_amdgcn_ds_bpermute(a1, pk[2 * s + 1][0]);
            int e3 = __builtin_amdgcn_ds_bpermute(a1, pk[2 * s + 0][1]);
            int g3 = __builtin_amdgcn_ds_bpermute(a1, pk[2 * s + 1][1]);
            i32x4 pbi;
            pbi[0] = hiq ? g0 : e0;
            pbi[1] = hiq ? g1 : e1;
            pbi[2] = hiq ? g2 : e2;
            pbi[3] = hiq ? g3 : e3;
            short8 pb = __builtin_bit_cast(short8, pbi);
            #pragma unroll
            for (int n = 0; n < 4; ++n)
                o[n] = __builtin_amdgcn_mfma_f32_16x16x32_bf16(va[n][s], pb, o[n], 0, 0, 0);
        }
    }

    l += __shfl_xor(l, 16); l += __shfl_xor(l, 32);
    const float inv = 1.f / l;
    const int bb = bh >> 4, h = bh & 15;
    #pragma unroll
    for (int n = 0; n < 4; ++n) {
        uint2 pk;
        pk.x = cvt_pk_bf16(o[n][0] * inv, o[n][1] * inv);
        pk.y = cvt_pk_bf16(o[n][2] * inv, o[n][3] * inv);
        *(uint2*)&y[((size_t)(bb * T_ + qrow)) * C_ + h * 64 + n * 16 + quad * 4] = pk;
    }
}

// ---------------------------------------------------------------------------
// Output projection: y[4096][1024] @ WprojT[1024][1024]^T + bias -> fp32 out.
// 128x64 tile (512 blocks, 48 KB LDS -> 3 blocks/CU).
// ---------------------------------------------------------------------------
__global__ __launch_bounds__(256, 3)
void proj_gemm(const u16* __restrict__ A, const u16* __restrict__ BT,
               const float* __restrict__ bias, float* __restrict__ out) {
    __shared__ __align__(16) u16 As[2 * 128 * 64];
    __shared__ __align__(16) u16 Bs[2 * 64 * 64];
    const int m0 = blockIdx.y * 128, n0 = blockIdx.x * 64;
    const int tid = threadIdx.x;
    const int lane = tid & 63, w = tid >> 6;
    const int l15 = lane & 15, quad = lane >> 4;
    const int row0 = (w & 1) * 64, col0 = (w >> 1) * 32;
    const int srow = lane >> 3;
    const int schunk = (lane & 7) ^ srow;
    f32x4 acc[4][2] = {};

    auto stage = [&](int buf, int k0) {
        #pragma unroll
        for (int j = 0; j < 4; ++j) {
            int rbase = w * 32 + j * 8;
            const u16* ga = A + (size_t)(m0 + rbase + srow) * 1024 + k0 + schunk * 8;
            __builtin_amdgcn_global_load_lds((const AS1 void*)ga,
                (AS3 void*)(As + buf * (128 * 64) + rbase * 64), 16, 0, 0);
        }
        #pragma unroll
        for (int j = 0; j < 2; ++j) {
            int rbase = w * 16 + j * 8;
            const u16* gb = BT + (size_t)(n0 + rbase + srow) * 1024 + k0 + schunk * 8;
            __builtin_amdgcn_global_load_lds((const AS1 void*)gb,
                (AS3 void*)(Bs + buf * (64 * 64) + rbase * 64), 16, 0, 0);
        }
    };

    stage(0, 0);
    #pragma unroll
    for (int it = 0; it < 16; ++it) {
        const int cur = it & 1;
        if (it + 1 < 16) {
            stage(cur ^ 1, (it + 1) * 64);
            asm volatile("s_waitcnt vmcnt(6)\n\ts_barrier" ::: "memory");
        } else {
            asm volatile("s_waitcnt vmcnt(0)\n\ts_barrier" ::: "memory");
        }
        const u16* Ac = As + cur * (128 * 64);
        const u16* Bc = Bs + cur * (64 * 64);
        #pragma unroll
        for (int s = 0; s < 2; ++s) {
            short8 a[4], b[2];
            #pragma unroll
            for (int rt = 0; rt < 4; ++rt) {
                int row = row0 + rt * 16 + l15;
                a[rt] = *(const short8*)&Ac[row * 64 + (((s * 4 + quad) ^ (l15 & 7)) * 8)];
            }
            #pragma unroll
            for (int ct = 0; ct < 2; ++ct) {
                int row = col0 + ct * 16 + l15;
                b[ct] = *(const short8*)&Bc[row * 64 + (((s * 4 + quad) ^ (l15 & 7)) * 8)];
            }
            #pragma unroll
            for (int rt = 0; rt < 4; ++rt)
                #pragma unroll
                for (int ct = 0; ct < 2; ++ct)
                    acc[rt][ct] = __builtin_amdgcn_mfma_f32_16x16x32_bf16(a[rt], b[ct], acc[rt][ct], 0, 0, 0);
        }
        asm volatile("s_waitcnt lgkmcnt(0)\n\ts_barrier" ::: "memory");
    }

    #pragma unroll
    for (int ct = 0; ct < 2; ++ct) {
        int n = n0 + col0 + ct * 16 + l15;
        float bv = bias[n];
        #pragma unroll
        for (int rt = 0; rt < 4; ++rt) {
            int mb = m0 + row0 + rt * 16 + quad * 4;
            f32x4 v4 = acc[rt][ct];
            #pragma unroll
            for (int r = 0; r < 4; ++r)
                out[(size_t)(mb + r) * 1024 + n] = v4[r] + bv;
        }
    }
}

// ---------------------------------------------------------------------------
extern "C" void kernel_launch(void* const* d_in, const int* in_sizes, int n_in,
                              void* d_out, int out_size, void* d_ws, size_t ws_size,
                              hipStream_t stream) {
    const float* x     = (const float*)d_in[0];
    const float* Wqkv  = (const float*)d_in[1];
    const float* bqkv  = (const float*)d_in[2];
    const float* Wproj = (const float*)d_in[3];
    const float* bproj = (const float*)d_in[4];

    u16* xb     = (u16*)d_ws;
    u16* WqkvT  = xb + (size_t)4 * 1024 * 1024;
    u16* WprojT = WqkvT + (size_t)3 * 1024 * 1024;
    u16* q      = WprojT + (size_t)1024 * 1024;
    u16* kk     = q + (size_t)4 * 1024 * 1024;
    u16* vT     = kk + (size_t)4 * 1024 * 1024;
    u16* y      = vT + (size_t)4 * 1024 * 1024;

    conv_all<<<5120, 256, 0, stream>>>(x, xb, Wqkv, WqkvT, Wproj, WprojT);
    qkv_gemm<<<256, 512, 0, stream>>>(xb, WqkvT, bqkv, q, kk, vT);
    attn<<<1024, 256, 0, stream>>>(q, kk, vT, y);
    proj_gemm<<<dim3(C_ / 64, BT_ / 128), 256, 0, stream>>>(y, WprojT, bproj, (float*)d_out);
}